// Round 1
// baseline (343.204 us; speedup 1.0000x reference)
//
#include <hip/hip_runtime.h>
#include <hip/hip_bf16.h>
#include <math.h>

#define INV_T (1.0f / 0.07f)

typedef __bf16 bf16x8 __attribute__((ext_vector_type(8)));
typedef float f32x4 __attribute__((ext_vector_type(4)));

__device__ __forceinline__ void gld16(const void* g, void* l) {
    __builtin_amdgcn_global_load_lds(
        (const __attribute__((address_space(1))) unsigned int*)g,
        (__attribute__((address_space(3))) unsigned int*)l,
        16, 0, 0);
}

// ---------------- zero S + acc ----------------
__global__ void zero_kernel(float* __restrict__ p, int n) {
    int i = blockIdx.x * blockDim.x + threadIdx.x;
    if (i < n) p[i] = 0.0f;
}

// ---------------- normalize + bf16 pack + positive dot ----------------
// one block per row i (B blocks, 256 threads); D=1024 -> 4 floats/thread
__global__ __launch_bounds__(256) void norm_kernel(
    const float4* __restrict__ f1, const float4* __restrict__ f2,
    ushort4* __restrict__ F, float* __restrict__ acc, int B) {
    const int i = blockIdx.x;
    const int t = threadIdx.x;

    float4 x = f1[i * 256 + t];
    float4 y = f2[i * 256 + t];

    float s1 = x.x * x.x + x.y * x.y + x.z * x.z + x.w * x.w;
    float s2 = y.x * y.x + y.y * y.y + y.z * y.z + y.w * y.w;
    float dd = x.x * y.x + x.y * y.y + x.z * y.z + x.w * y.w;

    // wave reduce (64 lanes)
    for (int o = 32; o > 0; o >>= 1) {
        s1 += __shfl_down(s1, o);
        s2 += __shfl_down(s2, o);
        dd += __shfl_down(dd, o);
    }
    __shared__ float red[4][3];
    const int wv = t >> 6, ln = t & 63;
    if (ln == 0) { red[wv][0] = s1; red[wv][1] = s2; red[wv][2] = dd; }
    __syncthreads();
    s1 = red[0][0] + red[1][0] + red[2][0] + red[3][0];
    s2 = red[0][1] + red[1][1] + red[2][1] + red[3][1];
    dd = red[0][2] + red[1][2] + red[2][2] + red[3][2];

    const float rn1 = 1.0f / fmaxf(sqrtf(s1), 1e-12f);
    const float rn2 = 1.0f / fmaxf(sqrtf(s2), 1e-12f);

    union { ushort4 u; __hip_bfloat16 h[4]; } p;
    p.h[0] = __float2bfloat16(x.x * rn1);
    p.h[1] = __float2bfloat16(x.y * rn1);
    p.h[2] = __float2bfloat16(x.z * rn1);
    p.h[3] = __float2bfloat16(x.w * rn1);
    F[(size_t)i * 256 + t] = p.u;
    p.h[0] = __float2bfloat16(y.x * rn2);
    p.h[1] = __float2bfloat16(y.y * rn2);
    p.h[2] = __float2bfloat16(y.z * rn2);
    p.h[3] = __float2bfloat16(y.w * rn2);
    F[(size_t)(B + i) * 256 + t] = p.u;

    if (t == 0) atomicAdd(acc, dd * rn1 * rn2);  // cosine(f1_i, f2_i)
}

// ---------------- fused sim-GEMM + exp + row-sum ----------------
// C = F * F^T (both row-major, B^T-style GEMM), 128x128 tile, BK=64,
// 4 waves in 2x2, each wave 64x64 via 4x4 of 16x16x32 bf16 MFMA.
__global__ __launch_bounds__(256, 2) void sim_kernel(
    const __hip_bfloat16* __restrict__ F, float* __restrict__ S,
    int N, int D) {
    __shared__ __align__(16) __hip_bfloat16 As[128][64];
    __shared__ __align__(16) __hip_bfloat16 Bs[128][64];

    const int tid  = threadIdx.x;
    const int wave = tid >> 6;
    const int lane = tid & 63;
    const int quad = lane >> 4;
    const int l16  = lane & 15;
    const int bRow = blockIdx.y * 128;
    const int bCol = blockIdx.x * 128;

    const int srow  = lane >> 3;        // 0..7  row-in-8 for staging
    const int skoff = (lane & 7) * 8;   // 0..56 k-offset (elements)

    const int waveRow = (wave >> 1) * 64;
    const int waveCol = (wave & 1) * 64;

    f32x4 acc[4][4];
#pragma unroll
    for (int mi = 0; mi < 4; ++mi)
#pragma unroll
        for (int ni = 0; ni < 4; ++ni)
            acc[mi][ni] = (f32x4){0.0f, 0.0f, 0.0f, 0.0f};

    for (int kb = 0; kb < D; kb += 64) {
        // stage A (rows of bRow strip) and B (rows of bCol strip): 16KB each
#pragma unroll
        for (int p = 0; p < 4; ++p) {
            const int rowT = (p * 4 + wave) * 8 + srow;  // 0..127
            gld16(&F[(size_t)(bRow + rowT) * D + kb + skoff], &As[rowT][skoff]);
            gld16(&F[(size_t)(bCol + rowT) * D + kb + skoff], &Bs[rowT][skoff]);
        }
        __syncthreads();

#pragma unroll
        for (int ks = 0; ks < 2; ++ks) {
            bf16x8 af[4], bfr[4];
#pragma unroll
            for (int mi = 0; mi < 4; ++mi)
                af[mi] = *(const bf16x8*)&As[waveRow + mi * 16 + l16][ks * 32 + quad * 8];
#pragma unroll
            for (int ni = 0; ni < 4; ++ni)
                bfr[ni] = *(const bf16x8*)&Bs[waveCol + ni * 16 + l16][ks * 32 + quad * 8];
#pragma unroll
            for (int mi = 0; mi < 4; ++mi)
#pragma unroll
                for (int ni = 0; ni < 4; ++ni)
                    acc[mi][ni] = __builtin_amdgcn_mfma_f32_16x16x32_bf16(
                        af[mi], bfr[ni], acc[mi][ni], 0, 0, 0);
        }
        __syncthreads();
    }

    // epilogue: t = exp((c-1)/T), mask diagonal, row-sum, atomic into S
#pragma unroll
    for (int mi = 0; mi < 4; ++mi) {
#pragma unroll
        for (int r = 0; r < 4; ++r) {
            const int gRow = bRow + waveRow + mi * 16 + quad * 4 + r;
            float v = 0.0f;
#pragma unroll
            for (int ni = 0; ni < 4; ++ni) {
                const int gCol = bCol + waveCol + ni * 16 + l16;
                const float c = acc[mi][ni][r];
                const float e = __expf((c - 1.0f) * INV_T);
                v += (gRow == gCol) ? 0.0f : e;
            }
            v += __shfl_xor(v, 1);
            v += __shfl_xor(v, 2);
            v += __shfl_xor(v, 4);
            v += __shfl_xor(v, 8);
            if (l16 == 0) atomicAdd(&S[gRow], v);
        }
    }
}

// ---------------- finalize: loss = 1/T + mean(log S) - pos_mean ----------------
__global__ __launch_bounds__(256) void finalize_kernel(
    const float* __restrict__ S, const float* __restrict__ acc,
    float* __restrict__ out, int N) {
    float s = 0.0f;
    for (int i = threadIdx.x; i < N; i += 256) s += logf(S[i]);
    for (int o = 32; o > 0; o >>= 1) s += __shfl_down(s, o);
    __shared__ float red[4];
    if ((threadIdx.x & 63) == 0) red[threadIdx.x >> 6] = s;
    __syncthreads();
    if (threadIdx.x == 0) {
        const float sl = red[0] + red[1] + red[2] + red[3];
        // loss = 1/T + (sum log S)/N - (sum posdot) * (2/T)/N
        out[0] = INV_T + sl / (float)N - acc[0] * (2.0f * INV_T / (float)N);
    }
}

extern "C" void kernel_launch(void* const* d_in, const int* in_sizes, int n_in,
                              void* d_out, int out_size, void* d_ws, size_t ws_size,
                              hipStream_t stream) {
    const int D = 1024;
    const int B = in_sizes[0] / D;  // 4096
    const int N = 2 * B;            // 8192

    const float* f1 = (const float*)d_in[0];
    const float* f2 = (const float*)d_in[1];

    __hip_bfloat16* F = (__hip_bfloat16*)d_ws;                       // N*D bf16 = 16 MB
    float* S  = (float*)((char*)d_ws + (size_t)N * D * sizeof(__hip_bfloat16));
    float* acc = S + N;                                              // 1 float

    zero_kernel<<<dim3((N + 1 + 255) / 256), dim3(256), 0, stream>>>(S, N + 1);
    norm_kernel<<<dim3(B), dim3(256), 0, stream>>>(
        (const float4*)f1, (const float4*)f2, (ushort4*)F, acc, B);
    sim_kernel<<<dim3(N / 128, N / 128), dim3(256), 0, stream>>>(F, S, N, D);
    finalize_kernel<<<dim3(1), dim3(256), 0, stream>>>(S, acc, (float*)d_out, N);
}

// Round 2
// 228.115 us; speedup vs baseline: 1.5045x; 1.5045x over previous
//
#include <hip/hip_runtime.h>
#include <hip/hip_bf16.h>
#include <math.h>

#define INV_T (1.0f / 0.07f)

typedef __bf16 bf16x8 __attribute__((ext_vector_type(8)));
typedef float f32x4 __attribute__((ext_vector_type(4)));

__device__ __forceinline__ void gld16(const void* g, void* l) {
    __builtin_amdgcn_global_load_lds(
        (const __attribute__((address_space(1))) unsigned int*)g,
        (__attribute__((address_space(3))) unsigned int*)l,
        16, 0, 0);
}

// ---------------- zero S + acc ----------------
__global__ void zero_kernel(float* __restrict__ p, int n) {
    int i = blockIdx.x * blockDim.x + threadIdx.x;
    if (i < n) p[i] = 0.0f;
}

// ---------------- normalize + bf16 pack + positive dot ----------------
__global__ __launch_bounds__(256) void norm_kernel(
    const float4* __restrict__ f1, const float4* __restrict__ f2,
    ushort4* __restrict__ F, float* __restrict__ acc, int B) {
    const int i = blockIdx.x;
    const int t = threadIdx.x;

    float4 x = f1[i * 256 + t];
    float4 y = f2[i * 256 + t];

    float s1 = x.x * x.x + x.y * x.y + x.z * x.z + x.w * x.w;
    float s2 = y.x * y.x + y.y * y.y + y.z * y.z + y.w * y.w;
    float dd = x.x * y.x + x.y * y.y + x.z * y.z + x.w * y.w;

    for (int o = 32; o > 0; o >>= 1) {
        s1 += __shfl_down(s1, o);
        s2 += __shfl_down(s2, o);
        dd += __shfl_down(dd, o);
    }
    __shared__ float red[4][3];
    const int wv = t >> 6, ln = t & 63;
    if (ln == 0) { red[wv][0] = s1; red[wv][1] = s2; red[wv][2] = dd; }
    __syncthreads();
    s1 = red[0][0] + red[1][0] + red[2][0] + red[3][0];
    s2 = red[0][1] + red[1][1] + red[2][1] + red[3][1];
    dd = red[0][2] + red[1][2] + red[2][2] + red[3][2];

    const float rn1 = 1.0f / fmaxf(sqrtf(s1), 1e-12f);
    const float rn2 = 1.0f / fmaxf(sqrtf(s2), 1e-12f);

    union { ushort4 u; __hip_bfloat16 h[4]; } p;
    p.h[0] = __float2bfloat16(x.x * rn1);
    p.h[1] = __float2bfloat16(x.y * rn1);
    p.h[2] = __float2bfloat16(x.z * rn1);
    p.h[3] = __float2bfloat16(x.w * rn1);
    F[(size_t)i * 256 + t] = p.u;
    p.h[0] = __float2bfloat16(y.x * rn2);
    p.h[1] = __float2bfloat16(y.y * rn2);
    p.h[2] = __float2bfloat16(y.z * rn2);
    p.h[3] = __float2bfloat16(y.w * rn2);
    F[(size_t)(B + i) * 256 + t] = p.u;

    if (t == 0) atomicAdd(acc, dd * rn1 * rn2);
}

// ---------------- fused sim-GEMM + exp + row/col-sum (upper triangle) ------
// Tiles (ti,tj) with ti<=tj only. Off-diagonal tiles contribute their exp
// values to BOTH row-sums (strip ti) and col-sums (strip tj). XOR-swizzled
// LDS: slot s at row r holds global k-chunk s^(r&7)  (chunk = 8 bf16 = 16B).
__global__ __launch_bounds__(256, 2) void sim_kernel(
    const __hip_bfloat16* __restrict__ F, float* __restrict__ S,
    int N, int D, int M /* = N/128 tiles per dim */) {
    __shared__ __align__(16) __hip_bfloat16 As[128][64];
    __shared__ __align__(16) __hip_bfloat16 Bs[128][64];

    // ---- decode linear block id -> upper-triangle (ti, tj), ti<=tj ----
    const int k = blockIdx.x;
    int ti = (int)((2 * M + 1 - sqrtf((float)((2 * M + 1) * (2 * M + 1) - 8 * k))) * 0.5f);
    if (ti >= M) ti = M - 1;
    if (ti < 0) ti = 0;
    while ((ti + 1) * M - ((ti + 1) * ti) / 2 <= k) ++ti;
    while (ti * M - (ti * (ti - 1)) / 2 > k) --ti;
    const int tj = ti + (k - (ti * M - (ti * (ti - 1)) / 2));
    const bool isDiag = (ti == tj);

    const int tid  = threadIdx.x;
    const int wave = tid >> 6;
    const int lane = tid & 63;
    const int quad = lane >> 4;
    const int l16  = lane & 15;
    const int bRow = ti * 128;
    const int bCol = tj * 128;

    // staging: lane -> (row-in-8, swizzled source chunk)
    const int srow     = lane >> 3;                         // 0..7
    const int ldsOff   = (lane & 7) * 8;                    // slot, elements
    const int srcOff   = ((lane & 7) ^ srow) * 8;           // global chunk, elements

    const int waveRow = (wave >> 1) * 64;
    const int waveCol = (wave & 1) * 64;
    const int swz = l16 & 7;                                // row&7 for all frag reads

    f32x4 acc[4][4];
#pragma unroll
    for (int mi = 0; mi < 4; ++mi)
#pragma unroll
        for (int ni = 0; ni < 4; ++ni)
            acc[mi][ni] = (f32x4){0.0f, 0.0f, 0.0f, 0.0f};

    for (int kb = 0; kb < D; kb += 64) {
#pragma unroll
        for (int p = 0; p < 4; ++p) {
            const int rowT = (p * 4 + wave) * 8 + srow;     // 0..127
            gld16(&F[(size_t)(bRow + rowT) * D + kb + srcOff], &As[rowT][ldsOff]);
            gld16(&F[(size_t)(bCol + rowT) * D + kb + srcOff], &Bs[rowT][ldsOff]);
        }
        __syncthreads();

#pragma unroll
        for (int ks = 0; ks < 2; ++ks) {
            const int slot = ((ks * 4 + quad) ^ swz) * 8;   // swizzled chunk, elements
            bf16x8 af[4], bfr[4];
#pragma unroll
            for (int mi = 0; mi < 4; ++mi)
                af[mi] = *(const bf16x8*)&As[waveRow + mi * 16 + l16][slot];
#pragma unroll
            for (int ni = 0; ni < 4; ++ni)
                bfr[ni] = *(const bf16x8*)&Bs[waveCol + ni * 16 + l16][slot];
#pragma unroll
            for (int mi = 0; mi < 4; ++mi)
#pragma unroll
                for (int ni = 0; ni < 4; ++ni)
                    acc[mi][ni] = __builtin_amdgcn_mfma_f32_16x16x32_bf16(
                        af[mi], bfr[ni], acc[mi][ni], 0, 0, 0);
        }
        __syncthreads();
    }

    // ---- epilogue: exp((c-1)/T); diag-mask; row sums; col sums if off-diag
#pragma unroll
    for (int mi = 0; mi < 4; ++mi)
#pragma unroll
        for (int ni = 0; ni < 4; ++ni)
#pragma unroll
            for (int r = 0; r < 4; ++r) {
                const int gRow = bRow + waveRow + mi * 16 + quad * 4 + r;
                const int gCol = bCol + waveCol + ni * 16 + l16;
                float e = __expf((acc[mi][ni][r] - 1.0f) * INV_T);
                if (isDiag && gRow == gCol) e = 0.0f;
                acc[mi][ni][r] = e;
            }

    // row sums (always)
#pragma unroll
    for (int mi = 0; mi < 4; ++mi)
#pragma unroll
        for (int r = 0; r < 4; ++r) {
            const int gRow = bRow + waveRow + mi * 16 + quad * 4 + r;
            float v = acc[mi][0][r] + acc[mi][1][r] + acc[mi][2][r] + acc[mi][3][r];
            v += __shfl_xor(v, 1);
            v += __shfl_xor(v, 2);
            v += __shfl_xor(v, 4);
            v += __shfl_xor(v, 8);
            if (l16 == 0) atomicAdd(&S[gRow], v);
        }

    // col sums (off-diagonal tiles only: the transpose contribution)
    if (!isDiag) {
#pragma unroll
        for (int ni = 0; ni < 4; ++ni) {
            float cv = 0.0f;
#pragma unroll
            for (int mi = 0; mi < 4; ++mi)
#pragma unroll
                for (int r = 0; r < 4; ++r)
                    cv += acc[mi][ni][r];
            cv += __shfl_xor(cv, 16);
            cv += __shfl_xor(cv, 32);
            if (quad == 0) atomicAdd(&S[bCol + waveCol + ni * 16 + l16], cv);
        }
    }
}

// ---------------- finalize ----------------
__global__ __launch_bounds__(256) void finalize_kernel(
    const float* __restrict__ S, const float* __restrict__ acc,
    float* __restrict__ out, int N) {
    float s = 0.0f;
    for (int i = threadIdx.x; i < N; i += 256) s += logf(S[i]);
    for (int o = 32; o > 0; o >>= 1) s += __shfl_down(s, o);
    __shared__ float red[4];
    if ((threadIdx.x & 63) == 0) red[threadIdx.x >> 6] = s;
    __syncthreads();
    if (threadIdx.x == 0) {
        const float sl = red[0] + red[1] + red[2] + red[3];
        out[0] = INV_T + sl / (float)N - acc[0] * (2.0f * INV_T / (float)N);
    }
}

extern "C" void kernel_launch(void* const* d_in, const int* in_sizes, int n_in,
                              void* d_out, int out_size, void* d_ws, size_t ws_size,
                              hipStream_t stream) {
    const int D = 1024;
    const int B = in_sizes[0] / D;  // 4096
    const int N = 2 * B;            // 8192
    const int M = N / 128;          // 64 tiles/dim
    const int ntiles = M * (M + 1) / 2;  // 2080

    const float* f1 = (const float*)d_in[0];
    const float* f2 = (const float*)d_in[1];

    __hip_bfloat16* F = (__hip_bfloat16*)d_ws;  // N*D bf16 = 16 MB
    float* S  = (float*)((char*)d_ws + (size_t)N * D * sizeof(__hip_bfloat16));
    float* acc = S + N;

    zero_kernel<<<dim3((N + 1 + 255) / 256), dim3(256), 0, stream>>>(S, N + 1);
    norm_kernel<<<dim3(B), dim3(256), 0, stream>>>(
        (const float4*)f1, (const float4*)f2, (ushort4*)F, acc, B);
    sim_kernel<<<dim3(ntiles), dim3(256), 0, stream>>>(F, S, N, D, M);
    finalize_kernel<<<dim3(1), dim3(256), 0, stream>>>(S, acc, (float*)d_out, N);
}

// Round 3
// 179.376 us; speedup vs baseline: 1.9133x; 1.2717x over previous
//
#include <hip/hip_runtime.h>
#include <hip/hip_bf16.h>
#include <math.h>

#define INV_T (1.0f / 0.07f)

typedef __bf16 bf16x8 __attribute__((ext_vector_type(8)));
typedef float f32x4 __attribute__((ext_vector_type(4)));

__device__ __forceinline__ void gld16(const void* g, void* l) {
    __builtin_amdgcn_global_load_lds(
        (const __attribute__((address_space(1))) unsigned int*)g,
        (__attribute__((address_space(3))) unsigned int*)l,
        16, 0, 0);
}

// ---------------- normalize + bf16 pack + positive dot + S-zero ------------
// one block per pair-row i; also zeroes S[i], S[B+i]; P[i] = cos(f1_i,f2_i)
__global__ __launch_bounds__(256) void norm_kernel(
    const float4* __restrict__ f1, const float4* __restrict__ f2,
    ushort4* __restrict__ F, float* __restrict__ S, float* __restrict__ P,
    int B) {
    const int i = blockIdx.x;
    const int t = threadIdx.x;

    float4 x = f1[i * 256 + t];
    float4 y = f2[i * 256 + t];

    float s1 = x.x * x.x + x.y * x.y + x.z * x.z + x.w * x.w;
    float s2 = y.x * y.x + y.y * y.y + y.z * y.z + y.w * y.w;
    float dd = x.x * y.x + x.y * y.y + x.z * y.z + x.w * y.w;

    for (int o = 32; o > 0; o >>= 1) {
        s1 += __shfl_down(s1, o);
        s2 += __shfl_down(s2, o);
        dd += __shfl_down(dd, o);
    }
    __shared__ float red[4][3];
    const int wv = t >> 6, ln = t & 63;
    if (ln == 0) { red[wv][0] = s1; red[wv][1] = s2; red[wv][2] = dd; }
    __syncthreads();
    s1 = red[0][0] + red[1][0] + red[2][0] + red[3][0];
    s2 = red[0][1] + red[1][1] + red[2][1] + red[3][1];
    dd = red[0][2] + red[1][2] + red[2][2] + red[3][2];

    const float rn1 = 1.0f / fmaxf(sqrtf(s1), 1e-12f);
    const float rn2 = 1.0f / fmaxf(sqrtf(s2), 1e-12f);

    union { ushort4 u; __hip_bfloat16 h[4]; } p;
    p.h[0] = __float2bfloat16(x.x * rn1);
    p.h[1] = __float2bfloat16(x.y * rn1);
    p.h[2] = __float2bfloat16(x.z * rn1);
    p.h[3] = __float2bfloat16(x.w * rn1);
    F[(size_t)i * 256 + t] = p.u;
    p.h[0] = __float2bfloat16(y.x * rn2);
    p.h[1] = __float2bfloat16(y.y * rn2);
    p.h[2] = __float2bfloat16(y.z * rn2);
    p.h[3] = __float2bfloat16(y.w * rn2);
    F[(size_t)(B + i) * 256 + t] = p.u;

    if (t == 0) {
        P[i] = dd * rn1 * rn2;
        S[i] = 0.0f;
        S[B + i] = 0.0f;
    }
}

// ---------------- fused sim-GEMM + exp + row/col-sum (upper triangle) ------
// 128x256 block tile (rows ti*128, cols tj*256), tiles with ti <= 2*tj+1.
// Rule: count ONLY strictly-upper elements (gRow < gCol); credit exp to both
// S[gRow] and S[gCol]. Each unordered pair is computed exactly once; diagonal
// excluded automatically. 4 waves in 2x2, each wave 64x128 (4x8 of 16x16x32).
// XOR-swizzled LDS: chunk slot s at row r holds global chunk s^(r&7).
__global__ __launch_bounds__(256, 2) void sim_kernel(
    const __hip_bfloat16* __restrict__ F, float* __restrict__ S,
    int N, int D) {
    __shared__ __align__(16) __hip_bfloat16 As[128][64];  // 16 KB
    __shared__ __align__(16) __hip_bfloat16 Bs[256][64];  // 32 KB

    // ---- decode linear block id -> (ti, tj): k = tj^2 + tj + ti ----
    const int k = blockIdx.x;
    int tj = (int)((sqrtf(4.0f * (float)k + 1.0f) - 1.0f) * 0.5f);
    while ((tj + 1) * (tj + 2) <= k) ++tj;
    while (tj * (tj + 1) > k) --tj;
    const int ti = k - tj * (tj + 1);  // in [0, 2*tj+2)
    const int bRow = ti * 128;
    const int bCol = tj * 256;

    const int tid  = threadIdx.x;
    const int wave = tid >> 6;
    const int lane = tid & 63;
    const int quad = lane >> 4;
    const int l16  = lane & 15;

    const int srow   = lane >> 3;                 // 0..7
    const int ldsOff = (lane & 7) * 8;            // dest slot (elements)
    const int srcOff = ((lane & 7) ^ srow) * 8;   // swizzled global chunk

    const int waveRow = (wave >> 1) * 64;
    const int waveCol = (wave & 1) * 128;
    const int swz = l16 & 7;

    f32x4 acc[4][8];
#pragma unroll
    for (int mi = 0; mi < 4; ++mi)
#pragma unroll
        for (int ni = 0; ni < 8; ++ni)
            acc[mi][ni] = (f32x4){0.0f, 0.0f, 0.0f, 0.0f};

    for (int kb = 0; kb < D; kb += 64) {
#pragma unroll
        for (int p = 0; p < 4; ++p) {
            const int rowT = (p * 4 + wave) * 8 + srow;   // 0..127
            gld16(&F[(size_t)(bRow + rowT) * D + kb + srcOff], &As[rowT][ldsOff]);
        }
#pragma unroll
        for (int p = 0; p < 8; ++p) {
            const int rowT = (p * 4 + wave) * 8 + srow;   // 0..255 (p*4+wave spans 0..31)
            gld16(&F[(size_t)(bCol + rowT) * D + kb + srcOff], &Bs[rowT][ldsOff]);
        }
        __syncthreads();

#pragma unroll
        for (int ks = 0; ks < 2; ++ks) {
            const int slot = ((ks * 4 + quad) ^ swz) * 8;
            bf16x8 bf[8];
#pragma unroll
            for (int ni = 0; ni < 8; ++ni)
                bf[ni] = *(const bf16x8*)&Bs[waveCol + ni * 16 + l16][slot];
#pragma unroll
            for (int mi = 0; mi < 4; ++mi) {
                const bf16x8 af = *(const bf16x8*)&As[waveRow + mi * 16 + l16][slot];
#pragma unroll
                for (int ni = 0; ni < 8; ++ni)
                    acc[mi][ni] = __builtin_amdgcn_mfma_f32_16x16x32_bf16(
                        af, bf[ni], acc[mi][ni], 0, 0, 0);
            }
        }
        __syncthreads();
    }

    // ---- epilogue: e = (gRow<gCol) ? exp((c-1)/T) : 0; row+col sums ----
#pragma unroll
    for (int mi = 0; mi < 4; ++mi)
#pragma unroll
        for (int ni = 0; ni < 8; ++ni)
#pragma unroll
            for (int r = 0; r < 4; ++r) {
                const int gRow = bRow + waveRow + mi * 16 + quad * 4 + r;
                const int gCol = bCol + waveCol + ni * 16 + l16;
                acc[mi][ni][r] = (gRow < gCol)
                    ? __expf((acc[mi][ni][r] - 1.0f) * INV_T) : 0.0f;
            }

    // row sums
#pragma unroll
    for (int mi = 0; mi < 4; ++mi)
#pragma unroll
        for (int r = 0; r < 4; ++r) {
            const int gRow = bRow + waveRow + mi * 16 + quad * 4 + r;
            float v = 0.0f;
#pragma unroll
            for (int ni = 0; ni < 8; ++ni) v += acc[mi][ni][r];
            v += __shfl_xor(v, 1);
            v += __shfl_xor(v, 2);
            v += __shfl_xor(v, 4);
            v += __shfl_xor(v, 8);
            if (l16 == 0) atomicAdd(&S[gRow], v);
        }

    // col sums (transpose contribution)
#pragma unroll
    for (int ni = 0; ni < 8; ++ni) {
        float cv = 0.0f;
#pragma unroll
        for (int mi = 0; mi < 4; ++mi)
#pragma unroll
            for (int r = 0; r < 4; ++r) cv += acc[mi][ni][r];
        cv += __shfl_xor(cv, 16);
        cv += __shfl_xor(cv, 32);
        if (quad == 0) atomicAdd(&S[bCol + waveCol + ni * 16 + l16], cv);
    }
}

// ---------------- finalize ----------------
__global__ __launch_bounds__(256) void finalize_kernel(
    const float* __restrict__ S, const float* __restrict__ P,
    float* __restrict__ out, int N, int B) {
    float s = 0.0f;
    for (int i = threadIdx.x; i < N; i += 256) s += __logf(S[i]);
    float pp = 0.0f;
    for (int i = threadIdx.x; i < B; i += 256) pp += P[i];
    for (int o = 32; o > 0; o >>= 1) {
        s += __shfl_down(s, o);
        pp += __shfl_down(pp, o);
    }
    __shared__ float red[4][2];
    if ((threadIdx.x & 63) == 0) {
        red[threadIdx.x >> 6][0] = s;
        red[threadIdx.x >> 6][1] = pp;
    }
    __syncthreads();
    if (threadIdx.x == 0) {
        const float sl = red[0][0] + red[1][0] + red[2][0] + red[3][0];
        const float ps = red[0][1] + red[1][1] + red[2][1] + red[3][1];
        out[0] = INV_T + sl / (float)N - ps * (2.0f * INV_T / (float)N);
    }
}

extern "C" void kernel_launch(void* const* d_in, const int* in_sizes, int n_in,
                              void* d_out, int out_size, void* d_ws, size_t ws_size,
                              hipStream_t stream) {
    const int D = 1024;
    const int B = in_sizes[0] / D;   // 4096
    const int N = 2 * B;             // 8192
    const int M2 = N / 256;          // 32 col-tiles
    const int ntiles = M2 * M2 + M2; // sum over tj of (2*tj+2) = 1056

    const float* f1 = (const float*)d_in[0];
    const float* f2 = (const float*)d_in[1];

    __hip_bfloat16* F = (__hip_bfloat16*)d_ws;  // N*D bf16 = 16 MB
    float* S = (float*)((char*)d_ws + (size_t)N * D * sizeof(__hip_bfloat16));
    float* P = S + N;  // B floats

    norm_kernel<<<dim3(B), dim3(256), 0, stream>>>(
        (const float4*)f1, (const float4*)f2, (ushort4*)F, S, P, B);
    sim_kernel<<<dim3(ntiles), dim3(256), 0, stream>>>(F, S, N, D);
    finalize_kernel<<<dim3(1), dim3(256), 0, stream>>>(S, P, (float*)d_out, N, B);
}